// Round 2
// baseline (5123.375 us; speedup 1.0000x reference)
//
#include <hip/hip_runtime.h>
#include <hip/hip_bf16.h>

// D-MPNN (chemprop MPNEncoder) forward. fp32 in/out; bf16 intermediates.
// Identity used to avoid storing inp = f_bonds@W_i:
//   relu(inp + m @ W_h) = relu([m | f_bonds] @ [[W_h];[W_i]])   (K = 300+147)
// Pipeline:
//   GEMM1: msg0 = relu(f_bonds @ W_i)                     [bf16]
//   2x:    gather_sum: amsg[a] = sum_j msg[a2b[a][j]]     [bf16]
//          GEMM2: msg' = relu([amsg[b2a]-msg[b2revb] | f_bonds] @ [[W_h];[W_i]])
//   gather_sum -> amsg
//   GEMM3: hidden = relu([f_atoms | amsg] @ W_o + b_o)    [bf16]
//   segment mean over atom_mol (atomics, fp32) -> d_out (fp32)

#define H_DIM 300
#define AF_DIM 133
#define BF_DIM 147
#define MAXNB 6

typedef __hip_bfloat16 bf16;

__device__ __forceinline__ float b2f(bf16 x) { return __bfloat162float(x); }
__device__ __forceinline__ bf16 f2b(float x) { return __float2bfloat16(x); }

// ---------------------------------------------------------------------------
// 64x64 tiled fp32 GEMM, 256 threads, 4x4 per thread, BK=16.
// MODE 1: A = f_bonds[M,147] (fp32), W = W_i[147,300]        -> relu
// MODE 2: A = [amsg[b2a]-msg[b2revb] (300, bf16) | f_bonds (147, fp32)]
//         W = rows<300 ? W_h : W_i                            -> relu
// MODE 3: A = [f_atoms (133, fp32) | amsg (300, bf16)], W = W_o, + b_o -> relu
// ---------------------------------------------------------------------------
template <int MODE>
__global__ __launch_bounds__(256) void gemm_kernel(
    const float* __restrict__ Af,   // M1/M2: f_bonds; M3: f_atoms
    const bf16* __restrict__ Ab1,   // M2: amsg; M3: amsg
    const bf16* __restrict__ Ab2,   // M2: msg_prev
    const int* __restrict__ idx1,   // M2: b2a
    const int* __restrict__ idx2,   // M2: b2revb
    const float* __restrict__ W1,   // M1: W_i; M2: W_h; M3: W_o
    const float* __restrict__ W2,   // M2: W_i
    const float* __restrict__ bias, // M3: b_o
    bf16* __restrict__ out,         // [M, N] bf16
    int M, int K, int N)
{
    __shared__ float As[16][64];
    __shared__ float Bs[16][64];

    const int m0 = blockIdx.x * 64;
    const int n0 = blockIdx.y * 64;
    const int t  = threadIdx.x;
    const int tx = t & 15;   // n micro-tile
    const int ty = t >> 4;   // m micro-tile

    // A-load: thread -> (row am, 4 consecutive k at ak)
    const int am = t >> 2;          // 0..63
    const int ak = (t & 3) * 4;     // 0,4,8,12
    // B-load: thread -> (k = bk, 4 consecutive n at bnq)
    const int bk  = t >> 4;         // 0..15
    const int bnq = (t & 15) * 4;   // 0..60

    const int gm   = m0 + am;
    const bool mok = (gm < M);

    int rowA = 0, rowB = 0;
    if (MODE == 2) {
        if (mok) { rowA = idx1[gm]; rowB = idx2[gm]; }
    }

    float acc[4][4];
#pragma unroll
    for (int i = 0; i < 4; ++i)
#pragma unroll
        for (int j = 0; j < 4; ++j) acc[i][j] = 0.f;

    const int numK = (K + 15) >> 4;
    for (int kt = 0; kt < numK; ++kt) {
        const int k0 = kt * 16;
        // ---- A tile -> As[k][m] ----
#pragma unroll
        for (int i = 0; i < 4; ++i) {
            const int gk = k0 + ak + i;
            float v = 0.f;
            if (mok && gk < K) {
                if (MODE == 1) {
                    v = Af[gm * BF_DIM + gk];
                } else if (MODE == 2) {
                    if (gk < H_DIM)
                        v = b2f(Ab1[rowA * H_DIM + gk]) - b2f(Ab2[rowB * H_DIM + gk]);
                    else
                        v = Af[gm * BF_DIM + (gk - H_DIM)];
                } else {
                    v = (gk < AF_DIM) ? Af[gm * AF_DIM + gk]
                                      : b2f(Ab1[gm * H_DIM + (gk - AF_DIM)]);
                }
            }
            As[ak + i][am] = v;
        }
        // ---- B tile -> Bs[k][n] ----
        {
            const int gk = k0 + bk;
#pragma unroll
            for (int j = 0; j < 4; ++j) {
                const int n  = bnq + j;
                const int gn = n0 + n;
                float v = 0.f;
                if (gk < K && gn < N) {
                    if (MODE == 2)
                        v = (gk < H_DIM) ? W1[gk * N + gn]
                                         : W2[(gk - H_DIM) * N + gn];
                    else
                        v = W1[gk * N + gn];
                }
                Bs[bk][n] = v;
            }
        }
        __syncthreads();
        // ---- compute ----
#pragma unroll
        for (int k = 0; k < 16; ++k) {
            const float4 a4 = *(const float4*)&As[k][ty * 4];
            const float4 b4 = *(const float4*)&Bs[k][tx * 4];
            const float a[4] = {a4.x, a4.y, a4.z, a4.w};
            const float b[4] = {b4.x, b4.y, b4.z, b4.w};
#pragma unroll
            for (int i = 0; i < 4; ++i)
#pragma unroll
                for (int j = 0; j < 4; ++j) acc[i][j] += a[i] * b[j];
        }
        __syncthreads();
    }

    // ---- epilogue: relu (+bias in MODE 3) -> bf16 ----
#pragma unroll
    for (int i = 0; i < 4; ++i) {
        const int m = m0 + ty * 4 + i;
        if (m >= M) break;
#pragma unroll
        for (int j = 0; j < 4; ++j) {
            const int n = n0 + tx * 4 + j;
            if (n >= N) continue;
            float v = acc[i][j];
            if (MODE == 3) v += bias[n];
            out[m * N + n] = f2b(fmaxf(v, 0.f));
        }
    }
}

// amsg[a][h] = sum_{j<6} msg[a2b[a][j]][h]  (bf16x2 over h, fp32 accumulate)
__global__ __launch_bounds__(256) void gather_sum_kernel(
    const bf16* __restrict__ msg, const int* __restrict__ a2b,
    bf16* __restrict__ amsg, int n_atoms)
{
    const int H2  = H_DIM / 2;  // 150
    const int idx = blockIdx.x * 256 + threadIdx.x;
    if (idx >= n_atoms * H2) return;
    const int a = idx / H2;
    const int h = idx - a * H2;
    const __hip_bfloat162* m2 = (const __hip_bfloat162*)msg;
    float sx = 0.f, sy = 0.f;
    const int base = a * MAXNB;
#pragma unroll
    for (int j = 0; j < MAXNB; ++j) {
        const int b = a2b[base + j];
        const __hip_bfloat162 u = m2[b * H2 + h];
        sx += __bfloat162float(u.x);
        sy += __bfloat162float(u.y);
    }
    __hip_bfloat162 r;
    r.x = f2b(sx);
    r.y = f2b(sy);
    ((__hip_bfloat162*)amsg)[a * H2 + h] = r;
}

__global__ __launch_bounds__(256) void seg_accum_kernel(
    const bf16* __restrict__ hidden, const int* __restrict__ atom_mol,
    float* __restrict__ sums, int n_atoms)
{
    const int idx = blockIdx.x * 256 + threadIdx.x;
    if (idx >= n_atoms * H_DIM) return;
    const int a = idx / H_DIM;
    const int h = idx - a * H_DIM;
    const int mol = atom_mol[a];
    atomicAdd(&sums[mol * H_DIM + h], b2f(hidden[idx]));
}

__global__ __launch_bounds__(256) void seg_count_kernel(
    const int* __restrict__ atom_mol, float* __restrict__ counts, int n_atoms)
{
    const int a = blockIdx.x * 256 + threadIdx.x;
    if (a >= n_atoms) return;
    atomicAdd(&counts[atom_mol[a]], 1.0f);
}

__global__ __launch_bounds__(256) void finalize_kernel(
    const float* __restrict__ sums, const float* __restrict__ counts,
    float* __restrict__ out, int n_mols)
{
    const int idx = blockIdx.x * 256 + threadIdx.x;
    if (idx >= n_mols * H_DIM) return;
    const int mol = idx / H_DIM;
    const float c = counts[mol];
    out[idx] = sums[idx] / fmaxf(c, 1.0f);
}

extern "C" void kernel_launch(void* const* d_in, const int* in_sizes, int n_in,
                              void* d_out, int out_size, void* d_ws, size_t ws_size,
                              hipStream_t stream)
{
    const float* f_atoms = (const float*)d_in[0];
    const float* f_bonds = (const float*)d_in[1];
    const float* W_i     = (const float*)d_in[2];
    const float* W_h     = (const float*)d_in[3];
    const float* W_o     = (const float*)d_in[4];
    const float* b_o     = (const float*)d_in[5];
    const int*  a2b      = (const int*)d_in[6];
    const int*  b2a      = (const int*)d_in[7];
    const int*  b2revb   = (const int*)d_in[8];
    const int*  atom_mol = (const int*)d_in[9];

    const int n_atoms = in_sizes[0] / AF_DIM;   // 100000
    const int n_bonds = in_sizes[1] / BF_DIM;   // 200000
    const int n_mols  = out_size / H_DIM;       // 4000

    // workspace layout (~305 MB)
    char* ws = (char*)d_ws;
    size_t off = 0;
    auto alloc = [&](size_t bytes) {
        size_t o = off;
        off += (bytes + 255) & ~(size_t)255;
        return o;
    };
    bf16*  msgA   = (bf16*)(ws + alloc((size_t)n_bonds * H_DIM * 2));
    bf16*  msgB   = (bf16*)(ws + alloc((size_t)n_bonds * H_DIM * 2));
    bf16*  amsg   = (bf16*)(ws + alloc((size_t)n_atoms * H_DIM * 2));
    float* sums   = (float*)(ws + alloc((size_t)n_mols * H_DIM * 4));
    float* counts = (float*)(ws + alloc((size_t)n_mols * 4));
    bf16*  hidden = msgB;  // msgB dead by GEMM3

    const dim3 blk(256);
    const dim3 gBond((n_bonds + 63) / 64, (H_DIM + 63) / 64);
    const dim3 gAtom((n_atoms + 63) / 64, (H_DIM + 63) / 64);
    const int gGather = (n_atoms * (H_DIM / 2) + 255) / 256;

    // msg0 = relu(f_bonds @ W_i)
    gemm_kernel<1><<<gBond, blk, 0, stream>>>(f_bonds, nullptr, nullptr, nullptr, nullptr,
                                              W_i, nullptr, nullptr, msgA,
                                              n_bonds, BF_DIM, H_DIM);

    // depth iteration 1: msgA -> msgB
    gather_sum_kernel<<<gGather, blk, 0, stream>>>(msgA, a2b, amsg, n_atoms);
    gemm_kernel<2><<<gBond, blk, 0, stream>>>(f_bonds, amsg, msgA, b2a, b2revb,
                                              W_h, W_i, nullptr, msgB,
                                              n_bonds, H_DIM + BF_DIM, H_DIM);

    // depth iteration 2: msgB -> msgA
    gather_sum_kernel<<<gGather, blk, 0, stream>>>(msgB, a2b, amsg, n_atoms);
    gemm_kernel<2><<<gBond, blk, 0, stream>>>(f_bonds, amsg, msgB, b2a, b2revb,
                                              W_h, W_i, nullptr, msgA,
                                              n_bonds, H_DIM + BF_DIM, H_DIM);

    // final atom aggregation from msgA
    gather_sum_kernel<<<gGather, blk, 0, stream>>>(msgA, a2b, amsg, n_atoms);

    // hidden = relu([f_atoms | amsg] @ W_o + b_o)
    gemm_kernel<3><<<gAtom, blk, 0, stream>>>(f_atoms, amsg, nullptr, nullptr, nullptr,
                                              W_o, nullptr, b_o, hidden,
                                              n_atoms, AF_DIM + H_DIM, H_DIM);

    // per-molecule mean
    hipMemsetAsync(sums, 0, (size_t)n_mols * H_DIM * 4, stream);
    hipMemsetAsync(counts, 0, (size_t)n_mols * 4, stream);
    seg_accum_kernel<<<((n_atoms * H_DIM) + 255) / 256, blk, 0, stream>>>(hidden, atom_mol, sums, n_atoms);
    seg_count_kernel<<<(n_atoms + 255) / 256, blk, 0, stream>>>(atom_mol, counts, n_atoms);
    finalize_kernel<<<((n_mols * H_DIM) + 255) / 256, blk, 0, stream>>>(sums, counts, (float*)d_out, n_mols);
}

// Round 3
// 1631.026 us; speedup vs baseline: 3.1412x; 3.1412x over previous
//
#include <hip/hip_runtime.h>
#include <hip/hip_bf16.h>
#include <stdint.h>

// D-MPNN (chemprop MPNEncoder) forward. fp32 in/out; bf16 intermediates, MFMA GEMMs.
// All intermediate matrices use a 320-col padded layout (cols 300..319 == 0) so
// every bf16 row is 16B-aligned and MFMA N-tiles divide evenly (320 = 20*16).
// Fused-K identity: relu(inp + m@W_h) = relu([m | f_bonds] @ [[W_h];[W_i]]),
// K = 320(msgdiff, padded) + 160(f_bonds, padded) = 480 = 15*32.

#define H_DIM 300
#define HP 320
#define AF_DIM 133
#define BF_DIM 147
#define MAXNB 6

typedef __hip_bfloat16 bf16;
typedef __attribute__((ext_vector_type(8))) short short8;
typedef __attribute__((ext_vector_type(4))) float f32x4;

__device__ __forceinline__ float b2f_raw(unsigned short u) {
    union { unsigned int i; float f; } v; v.i = ((unsigned int)u) << 16; return v.f;
}
__device__ __forceinline__ unsigned short f2b_raw(float f) {
    union { float f; unsigned int i; } v; v.f = f;
    unsigned int x = v.i;
    x += 0x7fffu + ((x >> 16) & 1u);   // RNE
    return (unsigned short)(x >> 16);
}

// ---------------------------------------------------------------------------
// Weight prep: Wt[n][k] (bf16, k-contiguous, n<320, k<nkt*32)
//   k < 320 : s1[k*300 + n]      (k < r1, n < 300)
//   k >= 320: s2[(k-320)*300 + n] (k-320 < r2, n < 300)
// ---------------------------------------------------------------------------
__global__ __launch_bounds__(256) void prep_wt(
    const float* __restrict__ s1, int r1,
    const float* __restrict__ s2, int r2,
    unsigned short* __restrict__ Wt, int nkt)
{
    const int Ktot = nkt * 32;
    const int idx = blockIdx.x * 256 + threadIdx.x;
    if (idx >= 320 * Ktot) return;
    const int n = idx % 320;
    const int k = idx / 320;
    float v = 0.f;
    if (n < H_DIM) {
        if (k < 320) { if (k < r1) v = s1[k * H_DIM + n]; }
        else { const int kk = k - 320; if (kk < r2) v = s2[kk * H_DIM + n]; }
    }
    Wt[n * Ktot + k] = f2b_raw(v);
}

// ---------------------------------------------------------------------------
// MFMA GEMM: out[M][320] = relu(A @ W (+bias)), A built on the fly.
// Block: 256 thr, tile 64(M) x 320(N), BK=32. Wave w: cols [80w, 80w+80).
// MODE 1: A[k<147] = f_bonds fp32 (stride 147);                     NKT=5
// MODE 2: A[k<300] = amsg[b2a[m]] - msg[b2revb[m]] (bf16 rows, stride 320)
//         A[320<=k<467] = f_bonds fp32 (stride 147);                NKT=15
// MODE 3: A[k<300] = amsg[m] (bf16, stride 320)
//         A[320<=k<453] = f_atoms fp32 (stride 133);                NKT=15
// LDS chunks XOR-swizzled: chunk c of row r lives at r*64 + (c^(r&3))*16.
// ---------------------------------------------------------------------------
template <int MODE>
__global__ __launch_bounds__(256) void mfma_gemm(
    const bf16* __restrict__ Ab,    // M2/M3: amsg
    const bf16* __restrict__ Ab2,   // M2: msg_prev
    const float* __restrict__ Afp,  // M1/M2: f_bonds; M3: f_atoms
    const int* __restrict__ idx1,   // M2: b2a
    const int* __restrict__ idx2,   // M2: b2revb
    const unsigned short* __restrict__ Wt,  // [320][NKT*32]
    const float* __restrict__ bias, // M3: b_o
    bf16* __restrict__ out,         // [M][320]
    int M)
{
    constexpr int NKT  = (MODE == 1) ? 5 : 15;
    constexpr int KTOT = NKT * 32;
    constexpr int FPW  = (MODE == 3) ? AF_DIM : BF_DIM;  // fp32 part width

    __shared__ char As[64 * 64];     // 64 rows x 32 bf16 (swizzled 16B chunks)
    __shared__ char Bs[320 * 64];    // 320 n-rows x 32 bf16 (swizzled)

    const int t    = threadIdx.x;
    const int m0   = blockIdx.x * 64;
    const int wave = t >> 6;
    const int lane = t & 63;
    const int l16  = lane & 15;
    const int quad = lane >> 4;
    const int swz  = ((quad ^ (l16 & 3)) << 4);  // byte offset of this lane's chunk

    // A-staging mapping: row am (0..63), chunk c (0..3) -> k-offset c*8 within kt
    const int am  = t >> 2;
    const int c   = t & 3;
    const int gm  = m0 + am;
    const bool mok = (gm < M);
    const int aoff = am * 64 + ((c ^ (am & 3)) << 4);

    long rowA = 0, rowB = 0;
    if (MODE == 2 && mok) { rowA = idx1[gm]; rowB = idx2[gm]; }

    f32x4 acc[4][5];
#pragma unroll
    for (int i = 0; i < 4; ++i)
#pragma unroll
        for (int j = 0; j < 5; ++j) acc[i][j] = (f32x4){0.f, 0.f, 0.f, 0.f};

    for (int kt = 0; kt < NKT; ++kt) {
        // ---------------- stage A ----------------
        uint4 aval = {0u, 0u, 0u, 0u};
        if (mok) {
            if (MODE == 1) {
                const int k = kt * 32 + c * 8;
                unsigned short* rp = (unsigned short*)&aval;
#pragma unroll
                for (int j = 0; j < 8; ++j) {
                    const int kk = k + j;
                    rp[j] = (kk < BF_DIM) ? f2b_raw(Afp[(long)gm * BF_DIM + kk]) : 0;
                }
            } else if (kt < 10) {
                const int k = kt * 32 + c * 8;
                if (MODE == 2) {
                    const uint4 a4 = *(const uint4*)((const char*)Ab  + (rowA * HP + k) * 2);
                    const uint4 b4 = *(const uint4*)((const char*)Ab2 + (rowB * HP + k) * 2);
                    const unsigned short* ap = (const unsigned short*)&a4;
                    const unsigned short* bp = (const unsigned short*)&b4;
                    unsigned short* rp = (unsigned short*)&aval;
#pragma unroll
                    for (int j = 0; j < 8; ++j)
                        rp[j] = f2b_raw(b2f_raw(ap[j]) - b2f_raw(bp[j]));
                } else {
                    aval = *(const uint4*)((const char*)Ab + ((long)gm * HP + k) * 2);
                }
            } else {
                const int k2 = (kt - 10) * 32 + c * 8;
                unsigned short* rp = (unsigned short*)&aval;
#pragma unroll
                for (int j = 0; j < 8; ++j) {
                    const int kk = k2 + j;
                    rp[j] = (kk < FPW) ? f2b_raw(Afp[(long)gm * FPW + kk]) : 0;
                }
            }
        }
        // ---------------- stage B (load to regs first) ----------------
        uint4 bval[5];
#pragma unroll
        for (int i = 0; i < 5; ++i) {
            const int boff = i * 4096 + t * 16;
            const int n  = boff >> 6;
            const int cc = (boff >> 4) & 3;
            const int ck = cc ^ (n & 3);
            bval[i] = *(const uint4*)((const char*)Wt + (long)n * (KTOT * 2) + kt * 64 + ck * 16);
        }
        __syncthreads();   // previous iteration's LDS reads done
        *(uint4*)(As + aoff) = aval;
#pragma unroll
        for (int i = 0; i < 5; ++i)
            *(uint4*)(Bs + i * 4096 + t * 16) = bval[i];
        __syncthreads();
        // ---------------- compute ----------------
        short8 afr[4];
#pragma unroll
        for (int mt = 0; mt < 4; ++mt)
            afr[mt] = *(const short8*)(As + mt * 1024 + l16 * 64 + swz);
#pragma unroll
        for (int nt = 0; nt < 5; ++nt) {
            const int nn = wave * 80 + nt * 16 + l16;   // (nn&3) == (l16&3)
            const short8 bfr = *(const short8*)(Bs + nn * 64 + swz);
#pragma unroll
            for (int mt = 0; mt < 4; ++mt)
                acc[mt][nt] = __builtin_amdgcn_mfma_f32_16x16x32_bf16(
                    afr[mt], bfr, acc[mt][nt], 0, 0, 0);
        }
    }

    // ---------------- epilogue: relu(+bias) -> bf16 ----------------
#pragma unroll
    for (int nt = 0; nt < 5; ++nt) {
        const int col = wave * 80 + nt * 16 + l16;
        float bv = 0.f;
        if (MODE == 3) bv = (col < H_DIM) ? bias[col] : 0.f;
#pragma unroll
        for (int mt = 0; mt < 4; ++mt) {
#pragma unroll
            for (int r = 0; r < 4; ++r) {
                const int row = m0 + mt * 16 + quad * 4 + r;
                if (row < M) {
                    const float v = acc[mt][nt][r] + bv;
                    ((unsigned short*)out)[(long)row * HP + col] = f2b_raw(fmaxf(v, 0.f));
                }
            }
        }
    }
}

// amsg[a][0:320] = sum_{j<6} msg[a2b[a][j]][0:320]; thread = (atom, 8-col chunk)
__global__ __launch_bounds__(256) void gather_sum_kernel(
    const bf16* __restrict__ msg, const int* __restrict__ a2b,
    bf16* __restrict__ amsg, int n_atoms)
{
    const int idx = blockIdx.x * 256 + threadIdx.x;
    if (idx >= n_atoms * (HP / 8)) return;
    const int a = idx / (HP / 8);
    const int cc = idx - a * (HP / 8);
    float s[8] = {0.f, 0.f, 0.f, 0.f, 0.f, 0.f, 0.f, 0.f};
    const int base = a * MAXNB;
#pragma unroll
    for (int j = 0; j < MAXNB; ++j) {
        const long b = a2b[base + j];
        const uint4 u = *(const uint4*)((const char*)msg + (b * HP + cc * 8) * 2);
        const unsigned short* up = (const unsigned short*)&u;
#pragma unroll
        for (int e = 0; e < 8; ++e) s[e] += b2f_raw(up[e]);
    }
    uint4 r;
    unsigned short* rp = (unsigned short*)&r;
#pragma unroll
    for (int e = 0; e < 8; ++e) rp[e] = f2b_raw(s[e]);
    *(uint4*)((char*)amsg + ((long)a * HP + cc * 8) * 2) = r;
}

// Per-molecule mean; atom_mol sorted ascending -> binary search range, no atomics.
__global__ __launch_bounds__(256) void seg_mean_kernel(
    const bf16* __restrict__ hidden, const int* __restrict__ atom_mol,
    float* __restrict__ out, int n_atoms)
{
    const int m = blockIdx.x;
    __shared__ int s_lo, s_hi;
    if (threadIdx.x == 0) {
        // lower_bound(m) and lower_bound(m+1)
        int lo = 0, hi = n_atoms;
        while (lo < hi) { int mid = (lo + hi) >> 1; if (atom_mol[mid] < m) lo = mid + 1; else hi = mid; }
        s_lo = lo;
        int lo2 = lo; hi = n_atoms;
        while (lo2 < hi) { int mid = (lo2 + hi) >> 1; if (atom_mol[mid] < m + 1) lo2 = mid + 1; else hi = mid; }
        s_hi = lo2;
    }
    __syncthreads();
    const int lo = s_lo, hi = s_hi;
    const float inv = 1.0f / (float)max(hi - lo, 1);
    for (int c = threadIdx.x; c < H_DIM; c += 256) {
        float s = 0.f;
        for (int a = lo; a < hi; ++a)
            s += b2f_raw(((const unsigned short*)hidden)[(long)a * HP + c]);
        out[(long)m * H_DIM + c] = s * inv;
    }
}

extern "C" void kernel_launch(void* const* d_in, const int* in_sizes, int n_in,
                              void* d_out, int out_size, void* d_ws, size_t ws_size,
                              hipStream_t stream)
{
    const float* f_atoms = (const float*)d_in[0];
    const float* f_bonds = (const float*)d_in[1];
    const float* W_i     = (const float*)d_in[2];
    const float* W_h     = (const float*)d_in[3];
    const float* W_o     = (const float*)d_in[4];
    const float* b_o     = (const float*)d_in[5];
    const int*  a2b      = (const int*)d_in[6];
    const int*  b2a      = (const int*)d_in[7];
    const int*  b2revb   = (const int*)d_in[8];
    const int*  atom_mol = (const int*)d_in[9];

    const int n_atoms = in_sizes[0] / AF_DIM;   // 100000
    const int n_bonds = in_sizes[1] / BF_DIM;   // 200000
    const int n_mols  = out_size / H_DIM;       // 4000

    char* ws = (char*)d_ws;
    size_t off = 0;
    auto alloc = [&](size_t bytes) {
        size_t o = off; off += (bytes + 255) & ~(size_t)255; return o;
    };
    bf16* msgA = (bf16*)(ws + alloc((size_t)n_bonds * HP * 2));   // 128 MB
    bf16* msgB = (bf16*)(ws + alloc((size_t)n_bonds * HP * 2));   // 128 MB
    bf16* amsg = (bf16*)(ws + alloc((size_t)n_atoms * HP * 2));   //  64 MB
    unsigned short* Wt1 = (unsigned short*)(ws + alloc(320 * 160 * 2));
    unsigned short* Wt2 = (unsigned short*)(ws + alloc(320 * 480 * 2));
    unsigned short* Wt3 = (unsigned short*)(ws + alloc(320 * 480 * 2));
    bf16* hidden = msgB;  // msgB dead after 2nd depth GEMM

    const dim3 blk(256);

    // weight prep (Wt3: amsg part = W_o rows 133.., atom part = W_o rows 0..132)
    prep_wt<<<(320 * 160 + 255) / 256, blk, 0, stream>>>(W_i, BF_DIM, nullptr, 0, Wt1, 5);
    prep_wt<<<(320 * 480 + 255) / 256, blk, 0, stream>>>(W_h, H_DIM, W_i, BF_DIM, Wt2, 15);
    prep_wt<<<(320 * 480 + 255) / 256, blk, 0, stream>>>(W_o + (size_t)AF_DIM * H_DIM, H_DIM,
                                                         W_o, AF_DIM, Wt3, 15);

    const int gB = (n_bonds + 63) / 64;   // 3125
    const int gA = (n_atoms + 63) / 64;   // 1563
    const int gG = (n_atoms * (HP / 8) + 255) / 256;

    // msg0 = relu(f_bonds @ W_i)
    mfma_gemm<1><<<gB, blk, 0, stream>>>(nullptr, nullptr, f_bonds, nullptr, nullptr,
                                         Wt1, nullptr, msgA, n_bonds);
    // depth 1: msgA -> msgB
    gather_sum_kernel<<<gG, blk, 0, stream>>>(msgA, a2b, amsg, n_atoms);
    mfma_gemm<2><<<gB, blk, 0, stream>>>(amsg, msgA, f_bonds, b2a, b2revb,
                                         Wt2, nullptr, msgB, n_bonds);
    // depth 2: msgB -> msgA
    gather_sum_kernel<<<gG, blk, 0, stream>>>(msgB, a2b, amsg, n_atoms);
    mfma_gemm<2><<<gB, blk, 0, stream>>>(amsg, msgB, f_bonds, b2a, b2revb,
                                         Wt2, nullptr, msgA, n_bonds);
    // final aggregation + readout
    gather_sum_kernel<<<gG, blk, 0, stream>>>(msgA, a2b, amsg, n_atoms);
    mfma_gemm<3><<<gA, blk, 0, stream>>>(amsg, nullptr, f_atoms, nullptr, nullptr,
                                         Wt3, b_o, hidden, n_atoms);
    // per-molecule mean
    seg_mean_kernel<<<n_mols, blk, 0, stream>>>(hidden, atom_mol, (float*)d_out, n_atoms);
}

// Round 4
// 936.174 us; speedup vs baseline: 5.4727x; 1.7422x over previous
//
#include <hip/hip_runtime.h>
#include <hip/hip_bf16.h>
#include <stdint.h>

// D-MPNN (chemprop MPNEncoder) forward. fp32 in/out; bf16 intermediates, MFMA GEMMs.
// Intermediates use a 320-col padded layout (cols 300..319 == 0): rows 16B-aligned,
// N-tiles divide evenly (320 = 20*16).
// Fused-K identity: relu(inp + m@W_h) = relu([m | f_bonds] @ [[W_h];[W_i]]), K=480.
// R4 changes vs R3 (which was LDS-BW bound, MfmaUtil 5.8%, 5x write amplification):
//  - B fragments load DIRECTLY from global (L2-resident 307KB weight), no LDS staging
//  - A double-buffered in LDS (2x4KB), 1 barrier/iter, global prefetch of kt+1
//  - epilogue stages 16-row C strips through LDS -> flat coalesced dwordx4 stores

#define H_DIM 300
#define HP 320
#define AF_DIM 133
#define BF_DIM 147
#define MAXNB 6

typedef __hip_bfloat16 bf16;
typedef __attribute__((ext_vector_type(8))) short short8;
typedef __attribute__((ext_vector_type(4))) float f32x4;

__device__ __forceinline__ float b2f_raw(unsigned short u) {
    union { unsigned int i; float f; } v; v.i = ((unsigned int)u) << 16; return v.f;
}
__device__ __forceinline__ unsigned short f2b_raw(float f) {
    union { float f; unsigned int i; } v; v.f = f;
    unsigned int x = v.i;
    x += 0x7fffu + ((x >> 16) & 1u);   // RNE
    return (unsigned short)(x >> 16);
}

// ---------------------------------------------------------------------------
// Weight prep: Wt[n][k] (bf16, k-contiguous, n<320, k<nkt*32)
//   k < 320 : s1[k*300 + n]      (k < r1, n < 300)
//   k >= 320: s2[(k-320)*300 + n] (k-320 < r2, n < 300)
// ---------------------------------------------------------------------------
__global__ __launch_bounds__(256) void prep_wt(
    const float* __restrict__ s1, int r1,
    const float* __restrict__ s2, int r2,
    unsigned short* __restrict__ Wt, int nkt)
{
    const int Ktot = nkt * 32;
    const int idx = blockIdx.x * 256 + threadIdx.x;
    if (idx >= 320 * Ktot) return;
    const int n = idx % 320;
    const int k = idx / 320;
    float v = 0.f;
    if (n < H_DIM) {
        if (k < 320) { if (k < r1) v = s1[k * H_DIM + n]; }
        else { const int kk = k - 320; if (kk < r2) v = s2[kk * H_DIM + n]; }
    }
    Wt[n * Ktot + k] = f2b_raw(v);
}

// ---------------------------------------------------------------------------
// MFMA GEMM: out[M][320] = relu(A @ W (+bias)). Block: 256 thr, tile 64x320,
// BK=32. Wave w: cols [80w, 80w+80).
// MODE 1: A[k<147] = f_bonds fp32 (stride 147);                     NKT=5
// MODE 2: A[k<300] = amsg[b2a[m]] - msg[b2revb[m]] (bf16, stride 320)
//         A[320<=k<467] = f_bonds fp32 (stride 147);                NKT=15
// MODE 3: A[k<300] = amsg[m] (bf16, stride 320)
//         A[320<=k<453] = f_atoms fp32 (stride 133);                NKT=15
// A LDS chunks XOR-swizzled: chunk c of row r at r*64 + (c^(r&3))*16.
// ---------------------------------------------------------------------------
template <int MODE>
__global__ __launch_bounds__(256) void mfma_gemm(
    const bf16* __restrict__ Ab,    // M2/M3: amsg
    const bf16* __restrict__ Ab2,   // M2: msg_prev
    const float* __restrict__ Afp,  // M1/M2: f_bonds; M3: f_atoms
    const int* __restrict__ idx1,   // M2: b2a
    const int* __restrict__ idx2,   // M2: b2revb
    const unsigned short* __restrict__ Wt,  // [320][NKT*32]
    const float* __restrict__ bias, // M3: b_o
    bf16* __restrict__ out,         // [M][320]
    int M)
{
    constexpr int NKT  = (MODE == 1) ? 5 : 15;
    constexpr int KTOT = NKT * 32;
    constexpr int FPW  = (MODE == 3) ? AF_DIM : BF_DIM;  // fp32 part width

    __shared__ char As[2][64 * 64];   // 2 x 4KB double-buffered A
    __shared__ char Cs[16 * 640];     // 10KB epilogue staging

    const int t    = threadIdx.x;
    const int m0   = blockIdx.x * 64;
    const int wave = t >> 6;
    const int lane = t & 63;
    const int l16  = lane & 15;
    const int quad = lane >> 4;
    const int swz  = ((quad ^ (l16 & 3)) << 4);

    // A-staging mapping: row am (0..63), chunk c (0..3)
    const int am  = t >> 2;
    const int c   = t & 3;
    const int gm  = m0 + am;
    const bool mok = (gm < M);
    const int aoff = am * 64 + ((c ^ (am & 3)) << 4);

    long rowA = 0, rowB = 0;
    if (MODE == 2 && mok) { rowA = idx1[gm]; rowB = idx2[gm]; }

    auto load_a = [&](int kt) -> uint4 {
        uint4 aval = {0u, 0u, 0u, 0u};
        if (!mok) return aval;
        if (MODE == 1) {
            const int k = kt * 32 + c * 8;
            unsigned short* rp = (unsigned short*)&aval;
#pragma unroll
            for (int j = 0; j < 8; ++j) {
                const int kk = k + j;
                rp[j] = (kk < BF_DIM) ? f2b_raw(Afp[(long)gm * BF_DIM + kk]) : 0;
            }
        } else if (kt < 10) {
            const int k = kt * 32 + c * 8;
            if (MODE == 2) {
                const uint4 a4 = *(const uint4*)((const char*)Ab  + (rowA * HP + k) * 2);
                const uint4 b4 = *(const uint4*)((const char*)Ab2 + (rowB * HP + k) * 2);
                const unsigned short* ap = (const unsigned short*)&a4;
                const unsigned short* bp = (const unsigned short*)&b4;
                unsigned short* rp = (unsigned short*)&aval;
#pragma unroll
                for (int j = 0; j < 8; ++j)
                    rp[j] = f2b_raw(b2f_raw(ap[j]) - b2f_raw(bp[j]));
            } else {
                aval = *(const uint4*)((const char*)Ab + ((long)gm * HP + k) * 2);
            }
        } else {
            const int k2 = (kt - 10) * 32 + c * 8;
            unsigned short* rp = (unsigned short*)&aval;
#pragma unroll
            for (int j = 0; j < 8; ++j) {
                const int kk = k2 + j;
                rp[j] = (kk < FPW) ? f2b_raw(Afp[(long)gm * FPW + kk]) : 0;
            }
        }
        return aval;
    };

    auto load_b = [&](int kt, short8* bfr) {
        const int kbase = kt * 32 + quad * 8;
#pragma unroll
        for (int nt = 0; nt < 5; ++nt) {
            const int nn = wave * 80 + nt * 16 + l16;
            bfr[nt] = *(const short8*)(Wt + (long)nn * KTOT + kbase);
        }
    };

    f32x4 acc[4][5];
#pragma unroll
    for (int i = 0; i < 4; ++i)
#pragma unroll
        for (int j = 0; j < 5; ++j) acc[i][j] = (f32x4){0.f, 0.f, 0.f, 0.f};

    // prologue: stage A(0), fetch B(0)
    uint4 aval = load_a(0);
    *(uint4*)(As[0] + aoff) = aval;
    short8 bfr[5];
    load_b(0, bfr);

    for (int kt = 0; kt < NKT; ++kt) {
        short8 bfr_n[5];
        if (kt + 1 < NKT) {                 // prefetch next iteration (global)
            aval = load_a(kt + 1);
            load_b(kt + 1, bfr_n);
        }
        __syncthreads();                    // As[kt&1] visible to all waves
        short8 afr[4];
#pragma unroll
        for (int mt = 0; mt < 4; ++mt)
            afr[mt] = *(const short8*)(As[kt & 1] + mt * 1024 + l16 * 64 + swz);
#pragma unroll
        for (int nt = 0; nt < 5; ++nt)
#pragma unroll
            for (int mt = 0; mt < 4; ++mt)
                acc[mt][nt] = __builtin_amdgcn_mfma_f32_16x16x32_bf16(
                    afr[mt], bfr[nt], acc[mt][nt], 0, 0, 0);
        if (kt + 1 < NKT) {
            *(uint4*)(As[(kt + 1) & 1] + aoff) = aval;  // safe: buffer last read in kt-1
#pragma unroll
            for (int nt = 0; nt < 5; ++nt) bfr[nt] = bfr_n[nt];
        }
    }

    // epilogue: per 16-row strip, LDS transpose -> coalesced 16B stores
    for (int mt = 0; mt < 4; ++mt) {
        __syncthreads();
#pragma unroll
        for (int nt = 0; nt < 5; ++nt) {
            const int col = wave * 80 + nt * 16 + l16;
            float bv = 0.f;
            if (MODE == 3) bv = (col < H_DIM) ? bias[col] : 0.f;
#pragma unroll
            for (int r = 0; r < 4; ++r) {
                const float v = fmaxf(acc[mt][nt][r] + bv, 0.f);
                ((unsigned short*)Cs)[(quad * 4 + r) * HP + col] = f2b_raw(v);
            }
        }
        __syncthreads();
        const int gr0 = m0 + mt * 16;
#pragma unroll
        for (int i = 0; i < 3; ++i) {       // 640 16B-chunks, 256 threads
            const int idx = i * 256 + t;
            if (idx < 640) {
                const int row = idx / 40;   // 40 chunks per 640B row
                if (gr0 + row < M)
                    *(uint4*)((char*)out + (long)(gr0 + row) * 640 + (idx - row * 40) * 16)
                        = *(const uint4*)(Cs + idx * 16);
            }
        }
    }
}

// amsg[a][0:320] = sum_{j<6} msg[a2b[a][j]][0:320]; thread = (atom, 8-col chunk)
__global__ __launch_bounds__(256) void gather_sum_kernel(
    const bf16* __restrict__ msg, const int* __restrict__ a2b,
    bf16* __restrict__ amsg, int n_atoms)
{
    const int idx = blockIdx.x * 256 + threadIdx.x;
    if (idx >= n_atoms * (HP / 8)) return;
    const int a = idx / (HP / 8);
    const int cc = idx - a * (HP / 8);
    float s[8] = {0.f, 0.f, 0.f, 0.f, 0.f, 0.f, 0.f, 0.f};
    const int base = a * MAXNB;
#pragma unroll
    for (int j = 0; j < MAXNB; ++j) {
        const long b = a2b[base + j];
        const uint4 u = *(const uint4*)((const char*)msg + (b * HP + cc * 8) * 2);
        const unsigned short* up = (const unsigned short*)&u;
#pragma unroll
        for (int e = 0; e < 8; ++e) s[e] += b2f_raw(up[e]);
    }
    uint4 r;
    unsigned short* rp = (unsigned short*)&r;
#pragma unroll
    for (int e = 0; e < 8; ++e) rp[e] = f2b_raw(s[e]);
    *(uint4*)((char*)amsg + ((long)a * HP + cc * 8) * 2) = r;
}

// Per-molecule mean; atom_mol sorted ascending -> binary search range, no atomics.
__global__ __launch_bounds__(256) void seg_mean_kernel(
    const bf16* __restrict__ hidden, const int* __restrict__ atom_mol,
    float* __restrict__ out, int n_atoms)
{
    const int m = blockIdx.x;
    __shared__ int s_lo, s_hi;
    if (threadIdx.x == 0) {
        int lo = 0, hi = n_atoms;
        while (lo < hi) { int mid = (lo + hi) >> 1; if (atom_mol[mid] < m) lo = mid + 1; else hi = mid; }
        s_lo = lo;
        int lo2 = lo; hi = n_atoms;
        while (lo2 < hi) { int mid = (lo2 + hi) >> 1; if (atom_mol[mid] < m + 1) lo2 = mid + 1; else hi = mid; }
        s_hi = lo2;
    }
    __syncthreads();
    const int lo = s_lo, hi = s_hi;
    const float inv = 1.0f / (float)max(hi - lo, 1);
    for (int cpass = 0; cpass < 2; ++cpass) {
        const int c = cpass * 256 + threadIdx.x;
        if (c >= H_DIM) break;
        float s = 0.f;
        for (int a = lo; a < hi; ++a)
            s += b2f_raw(((const unsigned short*)hidden)[(long)a * HP + c]);
        out[(long)m * H_DIM + c] = s * inv;
    }
}

extern "C" void kernel_launch(void* const* d_in, const int* in_sizes, int n_in,
                              void* d_out, int out_size, void* d_ws, size_t ws_size,
                              hipStream_t stream)
{
    const float* f_atoms = (const float*)d_in[0];
    const float* f_bonds = (const float*)d_in[1];
    const float* W_i     = (const float*)d_in[2];
    const float* W_h     = (const float*)d_in[3];
    const float* W_o     = (const float*)d_in[4];
    const float* b_o     = (const float*)d_in[5];
    const int*  a2b      = (const int*)d_in[6];
    const int*  b2a      = (const int*)d_in[7];
    const int*  b2revb   = (const int*)d_in[8];
    const int*  atom_mol = (const int*)d_in[9];

    const int n_atoms = in_sizes[0] / AF_DIM;   // 100000
    const int n_bonds = in_sizes[1] / BF_DIM;   // 200000
    const int n_mols  = out_size / H_DIM;       // 4000

    char* ws = (char*)d_ws;
    size_t off = 0;
    auto alloc = [&](size_t bytes) {
        size_t o = off; off += (bytes + 255) & ~(size_t)255; return o;
    };
    bf16* msgA = (bf16*)(ws + alloc((size_t)n_bonds * HP * 2));   // 128 MB
    bf16* msgB = (bf16*)(ws + alloc((size_t)n_bonds * HP * 2));   // 128 MB
    bf16* amsg = (bf16*)(ws + alloc((size_t)n_atoms * HP * 2));   //  64 MB
    unsigned short* Wt1 = (unsigned short*)(ws + alloc(320 * 160 * 2));
    unsigned short* Wt2 = (unsigned short*)(ws + alloc(320 * 480 * 2));
    unsigned short* Wt3 = (unsigned short*)(ws + alloc(320 * 480 * 2));
    bf16* hidden = msgB;  // msgB dead after 2nd depth GEMM

    const dim3 blk(256);

    // weight prep (Wt3: amsg part = W_o rows 133.., atom part = W_o rows 0..132)
    prep_wt<<<(320 * 160 + 255) / 256, blk, 0, stream>>>(W_i, BF_DIM, nullptr, 0, Wt1, 5);
    prep_wt<<<(320 * 480 + 255) / 256, blk, 0, stream>>>(W_h, H_DIM, W_i, BF_DIM, Wt2, 15);
    prep_wt<<<(320 * 480 + 255) / 256, blk, 0, stream>>>(W_o + (size_t)AF_DIM * H_DIM, H_DIM,
                                                         W_o, AF_DIM, Wt3, 15);

    const int gB = (n_bonds + 63) / 64;   // 3125
    const int gA = (n_atoms + 63) / 64;   // 1563
    const int gG = (n_atoms * (HP / 8) + 255) / 256;

    // msg0 = relu(f_bonds @ W_i)
    mfma_gemm<1><<<gB, blk, 0, stream>>>(nullptr, nullptr, f_bonds, nullptr, nullptr,
                                         Wt1, nullptr, msgA, n_bonds);
    // depth 1: msgA -> msgB
    gather_sum_kernel<<<gG, blk, 0, stream>>>(msgA, a2b, amsg, n_atoms);
    mfma_gemm<2><<<gB, blk, 0, stream>>>(amsg, msgA, f_bonds, b2a, b2revb,
                                         Wt2, nullptr, msgB, n_bonds);
    // depth 2: msgB -> msgA
    gather_sum_kernel<<<gG, blk, 0, stream>>>(msgB, a2b, amsg, n_atoms);
    mfma_gemm<2><<<gB, blk, 0, stream>>>(amsg, msgB, f_bonds, b2a, b2revb,
                                         Wt2, nullptr, msgA, n_bonds);
    // final aggregation + readout
    gather_sum_kernel<<<gG, blk, 0, stream>>>(msgA, a2b, amsg, n_atoms);
    mfma_gemm<3><<<gA, blk, 0, stream>>>(amsg, nullptr, f_atoms, nullptr, nullptr,
                                         Wt3, b_o, hidden, n_atoms);
    // per-molecule mean
    seg_mean_kernel<<<n_mols, blk, 0, stream>>>(hidden, atom_mol, (float*)d_out, n_atoms);
}